// Round 16
// baseline (291.370 us; speedup 1.0000x reference)
//
#include <hip/hip_runtime.h>

typedef float f32x4 __attribute__((ext_vector_type(4)));
typedef __bf16 bf16x8 __attribute__((ext_vector_type(8)));
typedef short s16x8 __attribute__((ext_vector_type(8)));

// Problem constants
#define NPOS   524288         // 8*16*64*64
#define KCODES 512
#define CDIM   64
#define THW    65536          // 16*64*64
#define MPOS   128            // positions per block
#define NTHR   256            // 4 waves
#define EPS2   6e-4f          // certification threshold (proven R12-R15)

// out layout (float32): [0, 33554432) quantized BCTHW; [33554432] loss; [33554433,+524288) indices
#define QOUT_N   33554432L
#define LOSSOFF  33554432L
#define IDX_OFF  33554433L

// ws: 0: double loss; 256: float eeg[512]; 4096: ushort ehi_g[8][512][8]; 69632: ushort emid_g[8][512][8]
//   (hi/mid are the bf16 split of -2*e, so MFMA accumulates  C + (-2 f.e))

__device__ inline unsigned int bf16_rne(unsigned int xb) {   // RN-even fp32->bf16 (no NaN/inf in data)
    return (xb + 0x7fffu + ((xb >> 16) & 1u)) >> 16;
}

#define GLOAD16(gp, lp) __builtin_amdgcn_global_load_lds( \
    (const __attribute__((address_space(1))) void*)(gp), \
    (__attribute__((address_space(3))) void*)(lp), 16, 0, 0)

__device__ inline f32x4 mf(s16x8 a, s16x8 b, f32x4 c) {
    return __builtin_amdgcn_mfma_f32_16x16x32_bf16(
        __builtin_bit_cast(bf16x8, a), __builtin_bit_cast(bf16x8, b), c, 0, 0, 0);
}

__device__ inline unsigned umin_(unsigned a, unsigned b) { return a < b ? a : b; }
__device__ inline unsigned med3u(unsigned a, unsigned b, unsigned c) {
    unsigned d;
    asm("v_med3_u32 %0, %1, %2, %3" : "=v"(d) : "v"(a), "v"(b), "v"(c));
    return d;
}
// insert k into sorted top-3 (m1<=m2<=m3): 3 ops (proven R14/R15)
#define INS3(k, M1, M2, M3) { unsigned _n1 = umin_((k), (M1)); \
    unsigned _n2 = med3u((k), (M1), (M2)); \
    unsigned _n3 = med3u((k), (M2), (M3)); \
    (M1) = _n1; (M2) = _n2; (M3) = _n3; }

// bit-exact distance key (proven chain, passing R9-R15): (dist_bits<<32)|code ; a stride = MPOS
__device__ inline unsigned long long exact_key(const float* a, const float* ffl,
                                               const float* eel, const float* __restrict__ emb,
                                               int pos, int q) {
    const float* er = emb + (long)q * 64;
    float acc = __fmul_rn(a[pos], er[0]);
    #pragma unroll
    for (int c = 1; c < 64; ++c) acc = __fmaf_rn(a[c * MPOS + pos], er[c], acc);
    float t1 = __fadd_rn(ffl[pos], eel[q]);
    float d  = __fmaf_rn(acc, -2.0f, t1);
    return ((unsigned long long)__float_as_uint(d) << 32) | (unsigned)q;
}

// ---------- prep: exact ee[q] (numpy pairwise-8) + bf16 hi/mid split of (-2e) ----------
extern "C" __global__ void vq_prep(const float* __restrict__ emb, float* __restrict__ ee,
                                   unsigned short* __restrict__ ehi, unsigned short* __restrict__ emid) {
    int q = threadIdx.x;               // 512 threads
    const float* er = emb + q * 64;
    float r[8];
    #pragma unroll
    for (int j = 0; j < 8; ++j) { float v = er[j]; r[j] = __fmul_rn(v, v); }
    #pragma unroll
    for (int t = 1; t < 8; ++t)
        #pragma unroll
        for (int j = 0; j < 8; ++j) { float v = er[t * 8 + j]; r[j] = __fadd_rn(r[j], __fmul_rn(v, v)); }
    float s0 = __fadd_rn(__fadd_rn(r[0], r[1]), __fadd_rn(r[2], r[3]));
    float s1 = __fadd_rn(__fadd_rn(r[4], r[5]), __fadd_rn(r[6], r[7]));
    ee[q] = __fadd_rn(s0, s1);
    #pragma unroll
    for (int c = 0; c < 64; ++c) {
        float xs = er[c] * -2.0f;                    // exact (power-of-2 scale + sign)
        unsigned int hb = bf16_rne(__float_as_uint(xs));
        float hif = __uint_as_float(hb << 16);
        float m = __fsub_rn(xs, hif);                // exact (Sterbenz)
        unsigned int mb = bf16_rne(__float_as_uint(m));
        long o = ((long)(c >> 3) * 512 + q) * 8 + (c & 7);   // [kg][code][8]
        ehi[o]  = (unsigned short)hb;
        emid[o] = (unsigned short)mb;
    }
}

// LDS layout (bytes), total 36424 -> 4 blocks/CU (16 waves/CU; 4096/1024 = 4.0 even rounds):
//   a:0 (32768) | eel:32768 (2048) | ffl:34816 (512) | kminl:35328 (512) | wl:35840 (512)
//   wcnt:36352 (8) | wred:36360 (32) | wsum:36392 (32)

extern "C" __global__ __launch_bounds__(NTHR, 4)
void vq_main(const float* __restrict__ x, const float* __restrict__ emb,
             float* __restrict__ out, double* __restrict__ lossws,
             const float* __restrict__ eeg,
             const unsigned short* __restrict__ ehi_g,
             const unsigned short* __restrict__ emid_g) {
    extern __shared__ char smem[];
    float*          a     = (float*)smem;
    float*          eel   = (float*)(smem + 32768);
    float*          ffl   = (float*)(smem + 34816);
    int*            kminl = (int*)(smem + 35328);
    int*            wl    = (int*)(smem + 35840);
    int*            wcnt  = (int*)(smem + 36352);
    unsigned long long* wred = (unsigned long long*)(smem + 36360);
    double*         wsum  = (double*)(smem + 36392);

    const int tid  = threadIdx.x;
    const int lane = tid & 63;
    const int w    = tid >> 6;                    // wave 0..3 -> positions [w*32, w*32+32)
    const int blk  = blockIdx.x;
    const int b    = blk >> 9;                    // 512 blocks per batch element
    const int r0   = (blk & 511) << 7;
    const long n0  = (long)blk * MPOS;

    if (tid == 0) *wcnt = 0;

    // ---- phase 1: stage x-tile [64][128] + eel (linear-dest gload_lds)
    const float* xb = x + (long)b * CDIM * THW + r0;
    #pragma unroll
    for (int k = 0; k < 8; ++k) {
        int g = tid + NTHR * k;                   // 16B-unit 0..2047
        int c = g >> 5, p4 = g & 31;
        GLOAD16(xb + (long)c * THW + p4 * 4, a + g * 4);
    }
    if (tid < 128) GLOAD16(eeg + tid * 4, eel + tid * 4);
    __syncthreads();   // drains vmcnt; a, eel ready

    // ---- phase 2a: ff[p] exact (numpy pairwise-8; proven)
    if (tid < 128) {
        float rr[8];
        #pragma unroll
        for (int j = 0; j < 8; ++j) { float v = a[j * MPOS + tid]; rr[j] = __fmul_rn(v, v); }
        #pragma unroll
        for (int t = 1; t < 8; ++t)
            #pragma unroll
            for (int j = 0; j < 8; ++j) {
                float v = a[(t * 8 + j) * MPOS + tid];
                rr[j] = __fadd_rn(rr[j], __fmul_rn(v, v));
            }
        float s0 = __fadd_rn(__fadd_rn(rr[0], rr[1]), __fadd_rn(rr[2], rr[3]));
        float s1 = __fadd_rn(__fadd_rn(rr[4], rr[5]), __fadd_rn(rr[6], rr[7]));
        ffl[tid] = __fadd_rn(s0, s1);
    }

    // ---- phase 2b: per-wave A-fragments built in registers (split in-lane; proven)
    s16x8 fah[2][2], fam[2][2];
    #pragma unroll
    for (int mt = 0; mt < 2; ++mt)
        #pragma unroll
        for (int ks = 0; ks < 2; ++ks) {
            int kg  = ks * 4 + (lane >> 4);
            int pin = w * 32 + mt * 16 + (lane & 15);
            s16x8 hv, mv;
            #pragma unroll
            for (int j = 0; j < 8; ++j) {
                float xv = a[(kg * 8 + j) * MPOS + pin];
                unsigned int hb = bf16_rne(__float_as_uint(xv));
                float hif = __uint_as_float(hb << 16);
                float m = __fsub_rn(xv, hif);
                unsigned int mb = bf16_rne(__float_as_uint(m));
                hv[j] = (short)hb; mv[j] = (short)mb;
            }
            fah[mt][ks] = hv; fam[mt][ks] = mv;
        }
    __syncthreads();   // ffl ready for all

    // ---- phase 4: BARRIER-FREE MFMA distance scan, E streamed from L2 into registers.
    // 32 tiles of 16 codes; 2-slot rotating prefetch, 2 tiles ahead (T14).
    unsigned m1[8], m2[8], m3[8];
    #pragma unroll
    for (int s = 0; s < 8; ++s) { m1[s] = 0xFFFFFFFFu; m2[s] = 0xFFFFFFFFu; m3[s] = 0xFFFFFFFFu; }

    const int kg0 = lane >> 4, cin = lane & 15;
    const long eb0 = ((long)(kg0    ) * 512 + cin) * 8;   // ushort offsets
    const long eb1 = ((long)(kg0 + 4) * 512 + cin) * 8;

    s16x8 Ah0, Ah1, Am0, Am1, Bh0, Bh1, Bm0, Bm1;
#define LOADT(S, t) { long o0 = eb0 + (long)(t) * 128, o1 = eb1 + (long)(t) * 128; \
    S##h0 = *(const s16x8*)(ehi_g + o0);  S##h1 = *(const s16x8*)(ehi_g + o1); \
    S##m0 = *(const s16x8*)(emid_g + o0); S##m1 = *(const s16x8*)(emid_g + o1); }
#define COMPT(S, t) { \
    unsigned code = (t) * 16 + cin; \
    float eev1 = __fadd_rn(eel[code], 1.0f); \
    f32x4 cseed = {eev1, eev1, eev1, eev1}; \
    _Pragma("unroll") \
    for (int mt = 0; mt < 2; ++mt) { \
        f32x4 aA = cseed, aB = {0.f, 0.f, 0.f, 0.f}; \
        aA = mf(fah[mt][0], S##h0, aA); \
        aB = mf(fah[mt][1], S##h1, aB); \
        aA = mf(fah[mt][0], S##m0, aA); \
        aB = mf(fah[mt][1], S##m1, aB); \
        aA = mf(fam[mt][0], S##h0, aA); \
        aB = mf(fam[mt][1], S##h1, aB); \
        _Pragma("unroll") \
        for (int rg = 0; rg < 4; ++rg) { \
            int s = mt * 4 + rg; \
            float v = __fadd_rn(aA[rg], aB[rg]); \
            unsigned kb = (__float_as_uint(v) & 0xFFFFFE00u) | code; \
            INS3(kb, m1[s], m2[s], m3[s]); \
        } } }

    LOADT(A, 0)
    LOADT(B, 1)
    #pragma unroll 1
    for (int t = 0; t < 32; t += 2) {
        COMPT(A, t)
        { int tn = (t + 2 < 32) ? t + 2 : 0; LOADT(A, tn) }   // refill slot A, 2 ahead
        COMPT(B, t + 1)
        { int tn = (t + 3 < 32) ? t + 3 : 1; LOADT(B, tn) }   // refill slot B, 2 ahead
    }
#undef LOADT
#undef COMPT

    // ---- phase 5: cross-lane top-3 merge (16 code-lanes) + certify (proven)
    #pragma unroll
    for (int s = 0; s < 8; ++s) {
        unsigned a1 = m1[s], a2 = m2[s], a3 = m3[s];
        #pragma unroll
        for (int m = 1; m <= 8; m <<= 1) {
            unsigned b1 = __shfl_xor(a1, m, 64);
            unsigned b2 = __shfl_xor(a2, m, 64);
            unsigned b3 = __shfl_xor(a3, m, 64);
            INS3(b1, a1, a2, a3);
            INS3(b2, a1, a2, a3);
            INS3(b3, a1, a2, a3);
        }
        if ((lane & 15) == 0) {
            int pos = w * 32 + (s >> 2) * 16 + (lane >> 4) * 4 + (s & 3);
            float f1 = __uint_as_float(a1 & 0xFFFFFE00u);
            float f2 = __uint_as_float(a2 & 0xFFFFFE00u);
            float f3 = __uint_as_float(a3 & 0xFFFFFE00u);
            int k1 = (int)(a1 & 511u), k2 = (int)(a2 & 511u);
            if (__fsub_rn(f2, f1) > EPS2) {
                kminl[pos] = k1;                                     // certified fast path
            } else if (__fsub_rn(f3, f1) > EPS2) {                   // candidates == {k1,k2}
                unsigned long long ka = exact_key(a, ffl, eel, emb, pos, k1);
                unsigned long long kb = exact_key(a, ffl, eel, emb, pos, k2);
                unsigned long long km = ka < kb ? ka : kb;
                kminl[pos] = (int)(km & 0xffffffffu);
            } else {
                wl[atomicAdd(wcnt, 1)] = pos;                        // rare: full exact scan
            }
        }
    }
    __syncthreads();

    // ---- phase 6: slow path — block-cooperative exact scan (256 threads x 2 codes)
    int nw = *wcnt;
    for (int i = 0; i < nw; ++i) {
        int pos = wl[i];
        unsigned long long ka = exact_key(a, ffl, eel, emb, pos, tid);
        unsigned long long kb = exact_key(a, ffl, eel, emb, pos, tid + 256);
        unsigned long long key = ka < kb ? ka : kb;
        #pragma unroll
        for (int m = 1; m < 64; m <<= 1) {
            unsigned long long p = __shfl_xor(key, m, 64);
            key = p < key ? p : key;
        }
        if (lane == 0) wred[w] = key;
        __syncthreads();
        if (tid == 0) {
            unsigned long long km = wred[0];
            #pragma unroll
            for (int j = 1; j < 4; ++j) km = wred[j] < km ? wred[j] : km;
            kminl[pos] = (int)(km & 0xffffffffu);
        }
        __syncthreads();
    }

    // ---- indices out (as float)
    if (tid < 128) out[IDX_OFF + n0 + tid] = (float)kminl[tid];

    // ---- quantized out (straight-through) + loss partial (proven epilogue)
    double lacc = 0.0;
    {
        const int col = (tid & 31) * 4;
        int iv[4];
        #pragma unroll
        for (int jj = 0; jj < 4; ++jj) iv[jj] = kminl[col + jj];
        float* ob = out + (long)b * CDIM * THW + r0;
        #pragma unroll
        for (int k = 0; k < 8; ++k) {
            int c = (tid >> 5) + 8 * k;
            float4 xv = *(const float4*)(a + c * MPOS + col);
            float4 ov;
            float q0 = emb[iv[0] * 64 + c];
            float d0 = __fsub_rn(q0, xv.x); ov.x = __fadd_rn(xv.x, d0); lacc += (double)__fmul_rn(d0, d0);
            float q1 = emb[iv[1] * 64 + c];
            float d1 = __fsub_rn(q1, xv.y); ov.y = __fadd_rn(xv.y, d1); lacc += (double)__fmul_rn(d1, d1);
            float q2 = emb[iv[2] * 64 + c];
            float d2 = __fsub_rn(q2, xv.z); ov.z = __fadd_rn(xv.z, d2); lacc += (double)__fmul_rn(d2, d2);
            float q3 = emb[iv[3] * 64 + c];
            float d3 = __fsub_rn(q3, xv.w); ov.w = __fadd_rn(xv.w, d3); lacc += (double)__fmul_rn(d3, d3);
            *(float4*)(ob + (long)c * THW + col) = ov;
        }
    }
    #pragma unroll
    for (int m = 1; m < 64; m <<= 1) lacc += __shfl_xor(lacc, m, 64);
    if (lane == 0) wsum[w] = lacc;
    __syncthreads();
    if (tid == 0) {
        double s = wsum[0] + wsum[1] + wsum[2] + wsum[3];
        atomicAdd(lossws, s);
    }
}

extern "C" __global__ void vq_finalize(const double* __restrict__ lossws,
                                       float* __restrict__ out) {
    if (threadIdx.x == 0) {
        float m = (float)(lossws[0] / (double)QOUT_N);
        out[LOSSOFF] = __fadd_rn(m, __fmul_rn(0.025f, m));
    }
}

extern "C" void kernel_launch(void* const* d_in, const int* in_sizes, int n_in,
                              void* d_out, int out_size, void* d_ws, size_t ws_size,
                              hipStream_t stream) {
    const float* x   = (const float*)d_in[0];
    const float* emb = (const float*)d_in[1];
    float* out = (float*)d_out;
    double* loss_ws = (double*)d_ws;
    float* ee_ws = (float*)((char*)d_ws + 256);
    unsigned short* ehi_ws  = (unsigned short*)((char*)d_ws + 4096);
    unsigned short* emid_ws = (unsigned short*)((char*)d_ws + 69632);

    hipMemsetAsync(d_ws, 0, sizeof(double), stream);
    hipLaunchKernelGGL(vq_prep, dim3(1), dim3(KCODES), 0, stream, emb, ee_ws, ehi_ws, emid_ws);

    dim3 grid(NPOS / MPOS);   // 4096
    dim3 block(NTHR);
    size_t shmem = 36424;
    hipLaunchKernelGGL(vq_main, grid, block, shmem, stream,
                       x, emb, out, loss_ws, ee_ws, ehi_ws, emid_ws);
    hipLaunchKernelGGL(vq_finalize, dim3(1), dim3(1), 0, stream,
                       (const double*)loss_ws, out);
}

// Round 17
// 277.346 us; speedup vs baseline: 1.0506x; 1.0506x over previous
//
#include <hip/hip_runtime.h>

typedef float f32x4 __attribute__((ext_vector_type(4)));
typedef __bf16 bf16x8 __attribute__((ext_vector_type(8)));
typedef short s16x8 __attribute__((ext_vector_type(8)));

// Problem constants
#define NPOS   524288         // 8*16*64*64
#define KCODES 512
#define CDIM   64
#define THW    65536          // 16*64*64
#define MPOS   128            // positions per block
#define NTHR   256            // 4 waves
#define EPS2   6e-4f          // certification threshold (proven R12-R15)

// out layout (float32): [0, 33554432) quantized BCTHW; [33554432] loss; [33554433,+524288) indices
#define QOUT_N   33554432L
#define LOSSOFF  33554432L
#define IDX_OFF  33554433L

// ws: 0: double loss; 256: float eeg[512]; 4096: ushort ehi_g[8][512][8]; 69632: ushort emid_g[8][512][8]
//   (hi/mid are the bf16 split of -2*e, so MFMA accumulates  C + (-2 f.e))

__device__ inline unsigned int bf16_rne(unsigned int xb) {   // RN-even fp32->bf16 (no NaN/inf in data)
    return (xb + 0x7fffu + ((xb >> 16) & 1u)) >> 16;
}

#define GLOAD16(gp, lp) __builtin_amdgcn_global_load_lds( \
    (const __attribute__((address_space(1))) void*)(gp), \
    (__attribute__((address_space(3))) void*)(lp), 16, 0, 0)

__device__ inline f32x4 mf(s16x8 a, s16x8 b, f32x4 c) {
    return __builtin_amdgcn_mfma_f32_16x16x32_bf16(
        __builtin_bit_cast(bf16x8, a), __builtin_bit_cast(bf16x8, b), c, 0, 0, 0);
}

__device__ inline unsigned umin_(unsigned a, unsigned b) { return a < b ? a : b; }
__device__ inline unsigned med3u(unsigned a, unsigned b, unsigned c) {
    unsigned d;
    asm("v_med3_u32 %0, %1, %2, %3" : "=v"(d) : "v"(a), "v"(b), "v"(c));
    return d;
}
// insert k into sorted top-3 (m1<=m2<=m3): 3 ops (proven R14/R15)
#define INS3(k, M1, M2, M3) { unsigned _n1 = umin_((k), (M1)); \
    unsigned _n2 = med3u((k), (M1), (M2)); \
    unsigned _n3 = med3u((k), (M2), (M3)); \
    (M1) = _n1; (M2) = _n2; (M3) = _n3; }

// bit-exact distance key (proven chain, passing R9-R15): (dist_bits<<32)|code ; a stride = MPOS
__device__ inline unsigned long long exact_key(const float* a, const float* ffl,
                                               const float* eel, const float* __restrict__ emb,
                                               int pos, int q) {
    const float* er = emb + (long)q * 64;
    float acc = __fmul_rn(a[pos], er[0]);
    #pragma unroll
    for (int c = 1; c < 64; ++c) acc = __fmaf_rn(a[c * MPOS + pos], er[c], acc);
    float t1 = __fadd_rn(ffl[pos], eel[q]);
    float d  = __fmaf_rn(acc, -2.0f, t1);
    return ((unsigned long long)__float_as_uint(d) << 32) | (unsigned)q;
}

// ---------- prep: exact ee[q] (numpy pairwise-8) + bf16 hi/mid split of (-2e) ----------
extern "C" __global__ void vq_prep(const float* __restrict__ emb, float* __restrict__ ee,
                                   unsigned short* __restrict__ ehi, unsigned short* __restrict__ emid) {
    int q = threadIdx.x;               // 512 threads
    const float* er = emb + q * 64;
    float r[8];
    #pragma unroll
    for (int j = 0; j < 8; ++j) { float v = er[j]; r[j] = __fmul_rn(v, v); }
    #pragma unroll
    for (int t = 1; t < 8; ++t)
        #pragma unroll
        for (int j = 0; j < 8; ++j) { float v = er[t * 8 + j]; r[j] = __fadd_rn(r[j], __fmul_rn(v, v)); }
    float s0 = __fadd_rn(__fadd_rn(r[0], r[1]), __fadd_rn(r[2], r[3]));
    float s1 = __fadd_rn(__fadd_rn(r[4], r[5]), __fadd_rn(r[6], r[7]));
    ee[q] = __fadd_rn(s0, s1);
    #pragma unroll
    for (int c = 0; c < 64; ++c) {
        float xs = er[c] * -2.0f;                    // exact (power-of-2 scale + sign)
        unsigned int hb = bf16_rne(__float_as_uint(xs));
        float hif = __uint_as_float(hb << 16);
        float m = __fsub_rn(xs, hif);                // exact (Sterbenz)
        unsigned int mb = bf16_rne(__float_as_uint(m));
        long o = ((long)(c >> 3) * 512 + q) * 8 + (c & 7);   // [kg][code][8]
        ehi[o]  = (unsigned short)hb;
        emid[o] = (unsigned short)mb;
    }
}

// LDS layout (bytes), total 36424 -> 4 blocks/CU at VGPR<=128:
//   a:0 (32768) | eel:32768 (2048) | ffl:34816 (512) | kminl:35328 (512) | wl:35840 (512)
//   wcnt:36352 (8) | wred:36360 (32) | wsum:36392 (32)

extern "C" __global__ __launch_bounds__(NTHR, 4)
void vq_main(const float* __restrict__ x, const float* __restrict__ emb,
             float* __restrict__ out, double* __restrict__ lossws,
             const float* __restrict__ eeg,
             const unsigned short* __restrict__ ehi_g,
             const unsigned short* __restrict__ emid_g) {
    extern __shared__ char smem[];
    float*          a     = (float*)smem;
    float*          eel   = (float*)(smem + 32768);
    float*          ffl   = (float*)(smem + 34816);
    int*            kminl = (int*)(smem + 35328);
    int*            wl    = (int*)(smem + 35840);
    int*            wcnt  = (int*)(smem + 36352);
    unsigned long long* wred = (unsigned long long*)(smem + 36360);
    double*         wsum  = (double*)(smem + 36392);

    const int tid  = threadIdx.x;
    const int lane = tid & 63;
    const int w    = tid >> 6;                    // wave 0..3 -> positions [w*32, w*32+32)
    const int blk  = blockIdx.x;
    const int b    = blk >> 9;                    // 512 blocks per batch element
    const int r0   = (blk & 511) << 7;
    const long n0  = (long)blk * MPOS;

    if (tid == 0) *wcnt = 0;

    // ---- phase 1: stage x-tile [64][128] + eel (linear-dest gload_lds)
    const float* xb = x + (long)b * CDIM * THW + r0;
    #pragma unroll
    for (int k = 0; k < 8; ++k) {
        int g = tid + NTHR * k;                   // 16B-unit 0..2047
        int c = g >> 5, p4 = g & 31;
        GLOAD16(xb + (long)c * THW + p4 * 4, a + g * 4);
    }
    if (tid < 128) GLOAD16(eeg + tid * 4, eel + tid * 4);
    __syncthreads();   // drains vmcnt; a, eel ready

    // ---- phase 2a: ff[p] exact (numpy pairwise-8; proven)
    if (tid < 128) {
        float rr[8];
        #pragma unroll
        for (int j = 0; j < 8; ++j) { float v = a[j * MPOS + tid]; rr[j] = __fmul_rn(v, v); }
        #pragma unroll
        for (int t = 1; t < 8; ++t)
            #pragma unroll
            for (int j = 0; j < 8; ++j) {
                float v = a[(t * 8 + j) * MPOS + tid];
                rr[j] = __fadd_rn(rr[j], __fmul_rn(v, v));
            }
        float s0 = __fadd_rn(__fadd_rn(rr[0], rr[1]), __fadd_rn(rr[2], rr[3]));
        float s1 = __fadd_rn(__fadd_rn(rr[4], rr[5]), __fadd_rn(rr[6], rr[7]));
        ffl[tid] = __fadd_rn(s0, s1);
    }

    // ---- phase 2b: per-wave A-fragments built in registers (split in-lane; proven)
    s16x8 fah[2][2], fam[2][2];
    #pragma unroll
    for (int mt = 0; mt < 2; ++mt)
        #pragma unroll
        for (int ks = 0; ks < 2; ++ks) {
            int kg  = ks * 4 + (lane >> 4);
            int pin = w * 32 + mt * 16 + (lane & 15);
            s16x8 hv, mv;
            #pragma unroll
            for (int j = 0; j < 8; ++j) {
                float xv = a[(kg * 8 + j) * MPOS + pin];
                unsigned int hb = bf16_rne(__float_as_uint(xv));
                float hif = __uint_as_float(hb << 16);
                float m = __fsub_rn(xv, hif);
                unsigned int mb = bf16_rne(__float_as_uint(m));
                hv[j] = (short)hb; mv[j] = (short)mb;
            }
            fah[mt][ks] = hv; fam[mt][ks] = mv;
        }
    __syncthreads();   // ffl ready for all

    // ---- phase 4: BARRIER-FREE MFMA distance scan, E streamed from L2.
    // Fully unrolled 32 tiles; per-tile loads are SSA values (no loop-carried
    // vector regs -> no scratch demotion); compiler schedules loads ahead.
    unsigned m1[8], m2[8], m3[8];
    #pragma unroll
    for (int s = 0; s < 8; ++s) { m1[s] = 0xFFFFFFFFu; m2[s] = 0xFFFFFFFFu; m3[s] = 0xFFFFFFFFu; }

    const int kg0 = lane >> 4, cin = lane & 15;
    const unsigned short* e0h = ehi_g  + ((long)(kg0    ) * 512 + cin) * 8;
    const unsigned short* e1h = ehi_g  + ((long)(kg0 + 4) * 512 + cin) * 8;
    const unsigned short* e0m = emid_g + ((long)(kg0    ) * 512 + cin) * 8;
    const unsigned short* e1m = emid_g + ((long)(kg0 + 4) * 512 + cin) * 8;

    #pragma unroll
    for (int t = 0; t < 32; ++t) {
        s16x8 h0 = *(const s16x8*)(e0h + t * 128);
        s16x8 h1 = *(const s16x8*)(e1h + t * 128);
        s16x8 q0 = *(const s16x8*)(e0m + t * 128);
        s16x8 q1 = *(const s16x8*)(e1m + t * 128);
        unsigned code = t * 16 + cin;
        float eev1 = __fadd_rn(eel[code], 1.0f);
        f32x4 cseed = {eev1, eev1, eev1, eev1};
        #pragma unroll
        for (int mt = 0; mt < 2; ++mt) {
            // two independent 3-chains; A-chain carries the C seed (proven R15)
            f32x4 aA = cseed, aB = {0.f, 0.f, 0.f, 0.f};
            aA = mf(fah[mt][0], h0, aA);
            aB = mf(fah[mt][1], h1, aB);
            aA = mf(fah[mt][0], q0, aA);
            aB = mf(fah[mt][1], q1, aB);
            aA = mf(fam[mt][0], h0, aA);
            aB = mf(fam[mt][1], h1, aB);
            #pragma unroll
            for (int rg = 0; rg < 4; ++rg) {
                int s = mt * 4 + rg;
                float v = __fadd_rn(aA[rg], aB[rg]);          // 1 + ee - 2 f.e
                unsigned kb = (__float_as_uint(v) & 0xFFFFFE00u) | code;
                INS3(kb, m1[s], m2[s], m3[s]);
            }
        }
    }

    // ---- phase 5: cross-lane top-3 merge (16 code-lanes) + certify (proven)
    #pragma unroll
    for (int s = 0; s < 8; ++s) {
        unsigned a1 = m1[s], a2 = m2[s], a3 = m3[s];
        #pragma unroll
        for (int m = 1; m <= 8; m <<= 1) {
            unsigned b1 = __shfl_xor(a1, m, 64);
            unsigned b2 = __shfl_xor(a2, m, 64);
            unsigned b3 = __shfl_xor(a3, m, 64);
            INS3(b1, a1, a2, a3);
            INS3(b2, a1, a2, a3);
            INS3(b3, a1, a2, a3);
        }
        if ((lane & 15) == 0) {
            int pos = w * 32 + (s >> 2) * 16 + (lane >> 4) * 4 + (s & 3);
            float f1 = __uint_as_float(a1 & 0xFFFFFE00u);
            float f2 = __uint_as_float(a2 & 0xFFFFFE00u);
            float f3 = __uint_as_float(a3 & 0xFFFFFE00u);
            int k1 = (int)(a1 & 511u), k2 = (int)(a2 & 511u);
            if (__fsub_rn(f2, f1) > EPS2) {
                kminl[pos] = k1;                                     // certified fast path
            } else if (__fsub_rn(f3, f1) > EPS2) {                   // candidates == {k1,k2}
                unsigned long long ka = exact_key(a, ffl, eel, emb, pos, k1);
                unsigned long long kb = exact_key(a, ffl, eel, emb, pos, k2);
                unsigned long long km = ka < kb ? ka : kb;
                kminl[pos] = (int)(km & 0xffffffffu);
            } else {
                wl[atomicAdd(wcnt, 1)] = pos;                        // rare: full exact scan
            }
        }
    }
    __syncthreads();

    // ---- phase 6: slow path — block-cooperative exact scan (256 threads x 2 codes)
    int nw = *wcnt;
    for (int i = 0; i < nw; ++i) {
        int pos = wl[i];
        unsigned long long ka = exact_key(a, ffl, eel, emb, pos, tid);
        unsigned long long kb = exact_key(a, ffl, eel, emb, pos, tid + 256);
        unsigned long long key = ka < kb ? ka : kb;
        #pragma unroll
        for (int m = 1; m < 64; m <<= 1) {
            unsigned long long p = __shfl_xor(key, m, 64);
            key = p < key ? p : key;
        }
        if (lane == 0) wred[w] = key;
        __syncthreads();
        if (tid == 0) {
            unsigned long long km = wred[0];
            #pragma unroll
            for (int j = 1; j < 4; ++j) km = wred[j] < km ? wred[j] : km;
            kminl[pos] = (int)(km & 0xffffffffu);
        }
        __syncthreads();
    }

    // ---- indices out (as float)
    if (tid < 128) out[IDX_OFF + n0 + tid] = (float)kminl[tid];

    // ---- quantized out (straight-through) + loss partial (proven epilogue)
    double lacc = 0.0;
    {
        const int col = (tid & 31) * 4;
        int iv[4];
        #pragma unroll
        for (int jj = 0; jj < 4; ++jj) iv[jj] = kminl[col + jj];
        float* ob = out + (long)b * CDIM * THW + r0;
        #pragma unroll
        for (int k = 0; k < 8; ++k) {
            int c = (tid >> 5) + 8 * k;
            float4 xv = *(const float4*)(a + c * MPOS + col);
            float4 ov;
            float q0 = emb[iv[0] * 64 + c];
            float d0 = __fsub_rn(q0, xv.x); ov.x = __fadd_rn(xv.x, d0); lacc += (double)__fmul_rn(d0, d0);
            float q1 = emb[iv[1] * 64 + c];
            float d1 = __fsub_rn(q1, xv.y); ov.y = __fadd_rn(xv.y, d1); lacc += (double)__fmul_rn(d1, d1);
            float q2 = emb[iv[2] * 64 + c];
            float d2 = __fsub_rn(q2, xv.z); ov.z = __fadd_rn(xv.z, d2); lacc += (double)__fmul_rn(d2, d2);
            float q3 = emb[iv[3] * 64 + c];
            float d3 = __fsub_rn(q3, xv.w); ov.w = __fadd_rn(xv.w, d3); lacc += (double)__fmul_rn(d3, d3);
            *(float4*)(ob + (long)c * THW + col) = ov;
        }
    }
    #pragma unroll
    for (int m = 1; m < 64; m <<= 1) lacc += __shfl_xor(lacc, m, 64);
    if (lane == 0) wsum[w] = lacc;
    __syncthreads();
    if (tid == 0) {
        double s = wsum[0] + wsum[1] + wsum[2] + wsum[3];
        atomicAdd(lossws, s);
    }
}

extern "C" __global__ void vq_finalize(const double* __restrict__ lossws,
                                       float* __restrict__ out) {
    if (threadIdx.x == 0) {
        float m = (float)(lossws[0] / (double)QOUT_N);
        out[LOSSOFF] = __fadd_rn(m, __fmul_rn(0.025f, m));
    }
}

extern "C" void kernel_launch(void* const* d_in, const int* in_sizes, int n_in,
                              void* d_out, int out_size, void* d_ws, size_t ws_size,
                              hipStream_t stream) {
    const float* x   = (const float*)d_in[0];
    const float* emb = (const float*)d_in[1];
    float* out = (float*)d_out;
    double* loss_ws = (double*)d_ws;
    float* ee_ws = (float*)((char*)d_ws + 256);
    unsigned short* ehi_ws  = (unsigned short*)((char*)d_ws + 4096);
    unsigned short* emid_ws = (unsigned short*)((char*)d_ws + 69632);

    hipMemsetAsync(d_ws, 0, sizeof(double), stream);
    hipLaunchKernelGGL(vq_prep, dim3(1), dim3(KCODES), 0, stream, emb, ee_ws, ehi_ws, emid_ws);

    dim3 grid(NPOS / MPOS);   // 4096
    dim3 block(NTHR);
    size_t shmem = 36424;
    hipLaunchKernelGGL(vq_main, grid, block, shmem, stream,
                       x, emb, out, loss_ws, ee_ws, ehi_ws, emid_ws);
    hipLaunchKernelGGL(vq_finalize, dim3(1), dim3(1), 0, stream,
                       (const double*)loss_ws, out);
}

// Round 18
// 226.693 us; speedup vs baseline: 1.2853x; 1.2234x over previous
//
#include <hip/hip_runtime.h>

typedef float f32x4 __attribute__((ext_vector_type(4)));
typedef __bf16 bf16x8 __attribute__((ext_vector_type(8)));
typedef short s16x8 __attribute__((ext_vector_type(8)));

// Problem constants
#define NPOS   524288         // 8*16*64*64
#define KCODES 512
#define CDIM   64
#define THW    65536          // 16*64*64
#define MPOS   128            // positions per block
#define NTHR   256            // 4 waves
#define NCH    8              // e-chunks of 64 codes (proven granularity)
#define EPS2   6e-4f          // certification threshold (proven R12-R15)

// out layout (float32): [0, 33554432) quantized BCTHW; [33554432] loss; [33554433,+524288) indices
#define QOUT_N   33554432L
#define LOSSOFF  33554432L
#define IDX_OFF  33554433L

// ws: 0: double loss; 256: float eeg[512]; 4096: ushort ehi_g[8][512][8]; 69632: ushort emid_g[8][512][8]
//   (hi/mid are the bf16 split of -2*e, so MFMA accumulates  C + (-2 f.e))

__device__ inline unsigned int bf16_rne(unsigned int xb) {   // RN-even fp32->bf16 (no NaN/inf in data)
    return (xb + 0x7fffu + ((xb >> 16) & 1u)) >> 16;
}

#define GLOAD16(gp, lp) __builtin_amdgcn_global_load_lds( \
    (const __attribute__((address_space(1))) void*)(gp), \
    (__attribute__((address_space(3))) void*)(lp), 16, 0, 0)

__device__ inline f32x4 mf(s16x8 a, s16x8 b, f32x4 c) {
    return __builtin_amdgcn_mfma_f32_16x16x32_bf16(
        __builtin_bit_cast(bf16x8, a), __builtin_bit_cast(bf16x8, b), c, 0, 0, 0);
}

__device__ inline unsigned umin_(unsigned a, unsigned b) { return a < b ? a : b; }
__device__ inline unsigned med3u(unsigned a, unsigned b, unsigned c) {
    unsigned d;
    asm("v_med3_u32 %0, %1, %2, %3" : "=v"(d) : "v"(a), "v"(b), "v"(c));
    return d;
}
// insert k into sorted top-3 (m1<=m2<=m3): 3 ops (proven R14/R15)
#define INS3(k, M1, M2, M3) { unsigned _n1 = umin_((k), (M1)); \
    unsigned _n2 = med3u((k), (M1), (M2)); \
    unsigned _n3 = med3u((k), (M2), (M3)); \
    (M1) = _n1; (M2) = _n2; (M3) = _n3; }

// bit-exact distance key (proven chain, passing R9-R15): (dist_bits<<32)|code ; a stride = MPOS
__device__ inline unsigned long long exact_key(const float* a, const float* ffl,
                                               const float* eel, const float* __restrict__ emb,
                                               int pos, int q) {
    const float* er = emb + (long)q * 64;
    float acc = __fmul_rn(a[pos], er[0]);
    #pragma unroll
    for (int c = 1; c < 64; ++c) acc = __fmaf_rn(a[c * MPOS + pos], er[c], acc);
    float t1 = __fadd_rn(ffl[pos], eel[q]);
    float d  = __fmaf_rn(acc, -2.0f, t1);
    return ((unsigned long long)__float_as_uint(d) << 32) | (unsigned)q;
}

// ---------- prep: exact ee[q] (numpy pairwise-8) + bf16 hi/mid split of (-2e) ----------
extern "C" __global__ void vq_prep(const float* __restrict__ emb, float* __restrict__ ee,
                                   unsigned short* __restrict__ ehi, unsigned short* __restrict__ emid) {
    int q = threadIdx.x;               // 512 threads
    const float* er = emb + q * 64;
    float r[8];
    #pragma unroll
    for (int j = 0; j < 8; ++j) { float v = er[j]; r[j] = __fmul_rn(v, v); }
    #pragma unroll
    for (int t = 1; t < 8; ++t)
        #pragma unroll
        for (int j = 0; j < 8; ++j) { float v = er[t * 8 + j]; r[j] = __fadd_rn(r[j], __fmul_rn(v, v)); }
    float s0 = __fadd_rn(__fadd_rn(r[0], r[1]), __fadd_rn(r[2], r[3]));
    float s1 = __fadd_rn(__fadd_rn(r[4], r[5]), __fadd_rn(r[6], r[7]));
    ee[q] = __fadd_rn(s0, s1);
    #pragma unroll
    for (int c = 0; c < 64; ++c) {
        float xs = er[c] * -2.0f;                    // exact (power-of-2 scale + sign)
        unsigned int hb = bf16_rne(__float_as_uint(xs));
        float hif = __uint_as_float(hb << 16);
        float m = __fsub_rn(xs, hif);                // exact (Sterbenz)
        unsigned int mb = bf16_rne(__float_as_uint(m));
        long o = ((long)(c >> 3) * 512 + q) * 8 + (c & 7);   // [kg][code][8]
        ehi[o]  = (unsigned short)hb;
        emid[o] = (unsigned short)mb;
    }
}

// LDS layout (bytes), total 52808 -> 3 blocks/CU (proven R11-R15):
//   a:0..32768 fp32[64][128] | ehc:32768 +8192 | emc:40960 +8192 | eel:49152 +2048
//   ffl:51200 +512 | kminl:51712 +512 | wl:52224 +512 | wcnt:52736 | wred:52744 | wsum:52776

extern "C" __global__ __launch_bounds__(NTHR, 3)
void vq_main(const float* __restrict__ x, const float* __restrict__ emb,
             float* __restrict__ out, double* __restrict__ lossws,
             const float* __restrict__ eeg,
             const unsigned short* __restrict__ ehi_g,
             const unsigned short* __restrict__ emid_g) {
    extern __shared__ char smem[];
    float*          a     = (float*)smem;
    unsigned short* ehc   = (unsigned short*)(smem + 32768);
    unsigned short* emc   = (unsigned short*)(smem + 40960);
    float*          eel   = (float*)(smem + 49152);
    float*          ffl   = (float*)(smem + 51200);
    int*            kminl = (int*)(smem + 51712);
    int*            wl    = (int*)(smem + 52224);
    int*            wcnt  = (int*)(smem + 52736);
    unsigned long long* wred = (unsigned long long*)(smem + 52744);
    double*         wsum  = (double*)(smem + 52776);

    const int tid  = threadIdx.x;
    const int lane = tid & 63;
    const int w    = tid >> 6;                    // wave 0..3 -> positions [w*32, w*32+32)
    const int blk  = blockIdx.x;
    const int b    = blk >> 9;                    // 512 blocks per batch element
    const int r0   = (blk & 511) << 7;
    const long n0  = (long)blk * MPOS;

    if (tid == 0) *wcnt = 0;

    // ---- phase 1: stage x-tile [64][128] + eel + e-chunk 0 (linear-dest gload_lds)
    const float* xb = x + (long)b * CDIM * THW + r0;
    #pragma unroll
    for (int k = 0; k < 8; ++k) {
        int g = tid + NTHR * k;                   // 16B-unit 0..2047
        int c = g >> 5, p4 = g & 31;
        GLOAD16(xb + (long)c * THW + p4 * 4, a + g * 4);
    }
    if (tid < 128) GLOAD16(eeg + tid * 4, eel + tid * 4);
    #pragma unroll
    for (int k = 0; k < 2; ++k) {
        int u = tid + NTHR * k, kg = u >> 6, cc = u & 63;
        long go = ((long)kg * 512 + cc) * 8;      // chunk 0
        GLOAD16(ehi_g + go, ehc + u * 8);
        GLOAD16(emid_g + go, emc + u * 8);
    }
    __syncthreads();   // drains vmcnt; a, eel, chunk 0 ready

    // ---- phase 2a: ff[p] exact (numpy pairwise-8; proven)
    if (tid < 128) {
        float rr[8];
        #pragma unroll
        for (int j = 0; j < 8; ++j) { float v = a[j * MPOS + tid]; rr[j] = __fmul_rn(v, v); }
        #pragma unroll
        for (int t = 1; t < 8; ++t)
            #pragma unroll
            for (int j = 0; j < 8; ++j) {
                float v = a[(t * 8 + j) * MPOS + tid];
                rr[j] = __fadd_rn(rr[j], __fmul_rn(v, v));
            }
        float s0 = __fadd_rn(__fadd_rn(rr[0], rr[1]), __fadd_rn(rr[2], rr[3]));
        float s1 = __fadd_rn(__fadd_rn(rr[4], rr[5]), __fadd_rn(rr[6], rr[7]));
        ffl[tid] = __fadd_rn(s0, s1);
    }

    // ---- phase 2b: per-wave A-fragments built in registers (split in-lane; proven)
    s16x8 fah[2][2], fam[2][2];
    #pragma unroll
    for (int mt = 0; mt < 2; ++mt)
        #pragma unroll
        for (int ks = 0; ks < 2; ++ks) {
            int kg  = ks * 4 + (lane >> 4);
            int pin = w * 32 + mt * 16 + (lane & 15);
            s16x8 hv, mv;
            #pragma unroll
            for (int j = 0; j < 8; ++j) {
                float xv = a[(kg * 8 + j) * MPOS + pin];
                unsigned int hb = bf16_rne(__float_as_uint(xv));
                float hif = __uint_as_float(hb << 16);
                float m = __fsub_rn(xv, hif);
                unsigned int mb = bf16_rne(__float_as_uint(m));
                hv[j] = (short)hb; mv[j] = (short)mb;
            }
            fah[mt][ks] = hv; fam[mt][ks] = mv;
        }
    __syncthreads();   // ffl ready for all

    // ---- phase 4: MFMA distance scan; key = bits(1 + ee - 2 f.e) masked | code
    // chain A is C-seeded with (1+ee); B operands carry -2e, so no per-rg fma needed.
    unsigned m1[8], m2[8], m3[8];
    #pragma unroll
    for (int s = 0; s < 8; ++s) { m1[s] = 0xFFFFFFFFu; m2[s] = 0xFFFFFFFFu; m3[s] = 0xFFFFFFFFu; }

    #pragma unroll 1
    for (int ch = 0; ch < NCH; ++ch) {
        // T14: prefetch next chunk into regs; latency hides under this chunk's compute
        f32x4 ph0, ph1, pm0, pm1;
        if (ch < NCH - 1) {
            int u0 = tid,        kg0p = u0 >> 6, cc0 = u0 & 63;
            int u1 = tid + NTHR, kg1p = u1 >> 6, cc1 = u1 & 63;
            long g0 = ((long)kg0p * 512 + (long)(ch + 1) * 64 + cc0) * 8;
            long g1 = ((long)kg1p * 512 + (long)(ch + 1) * 64 + cc1) * 8;
            ph0 = *(const f32x4*)(ehi_g + g0);
            ph1 = *(const f32x4*)(ehi_g + g1);
            pm0 = *(const f32x4*)(emid_g + g0);
            pm1 = *(const f32x4*)(emid_g + g1);
        }

        #pragma unroll
        for (int nt = 0; nt < 4; ++nt) {
            int kg0 = lane >> 4, cin = nt * 16 + (lane & 15);
            s16x8 bh0 = *(const s16x8*)(ehc + ((kg0    ) * 64 + cin) * 8);
            s16x8 bh1 = *(const s16x8*)(ehc + ((kg0 + 4) * 64 + cin) * 8);
            s16x8 bm0 = *(const s16x8*)(emc + ((kg0    ) * 64 + cin) * 8);
            s16x8 bm1 = *(const s16x8*)(emc + ((kg0 + 4) * 64 + cin) * 8);
            unsigned code = ch * 64 + nt * 16 + (lane & 15);
            float eev1 = __fadd_rn(eel[code], 1.0f);
            f32x4 cseed = {eev1, eev1, eev1, eev1};
            #pragma unroll
            for (int mt = 0; mt < 2; ++mt) {
                // two independent 3-chains; A-chain carries the C seed
                f32x4 aA = cseed, aB = {0.f, 0.f, 0.f, 0.f};
                aA = mf(fah[mt][0], bh0, aA);
                aB = mf(fah[mt][1], bh1, aB);
                aA = mf(fah[mt][0], bm0, aA);
                aB = mf(fah[mt][1], bm1, aB);
                aA = mf(fam[mt][0], bh0, aA);
                aB = mf(fam[mt][1], bh1, aB);
                #pragma unroll
                for (int rg = 0; rg < 4; ++rg) {
                    int s = mt * 4 + rg;
                    float v = __fadd_rn(aA[rg], aB[rg]);          // 1 + ee - 2 f.e
                    unsigned kb = (__float_as_uint(v) & 0xFFFFFE00u) | code;
                    INS3(kb, m1[s], m2[s], m3[s]);
                }
            }
        }

        if (ch < NCH - 1) {
            __syncthreads();              // all waves done reading ehc/emc
            *(f32x4*)(ehc + tid * 8)          = ph0;    // vmcnt wait auto-inserted
            *(f32x4*)(ehc + (tid + NTHR) * 8) = ph1;
            *(f32x4*)(emc + tid * 8)          = pm0;
            *(f32x4*)(emc + (tid + NTHR) * 8) = pm1;
            __syncthreads();              // writes visible to all waves
        }
    }

    // ---- phase 5: cross-lane top-3 merge (16 code-lanes) + certify (proven)
    #pragma unroll
    for (int s = 0; s < 8; ++s) {
        unsigned a1 = m1[s], a2 = m2[s], a3 = m3[s];
        #pragma unroll
        for (int m = 1; m <= 8; m <<= 1) {
            unsigned b1 = __shfl_xor(a1, m, 64);
            unsigned b2 = __shfl_xor(a2, m, 64);
            unsigned b3 = __shfl_xor(a3, m, 64);
            INS3(b1, a1, a2, a3);
            INS3(b2, a1, a2, a3);
            INS3(b3, a1, a2, a3);
        }
        if ((lane & 15) == 0) {
            int pos = w * 32 + (s >> 2) * 16 + (lane >> 4) * 4 + (s & 3);
            float f1 = __uint_as_float(a1 & 0xFFFFFE00u);
            float f2 = __uint_as_float(a2 & 0xFFFFFE00u);
            float f3 = __uint_as_float(a3 & 0xFFFFFE00u);
            int k1 = (int)(a1 & 511u), k2 = (int)(a2 & 511u);
            if (__fsub_rn(f2, f1) > EPS2) {
                kminl[pos] = k1;                                     // certified fast path
            } else if (__fsub_rn(f3, f1) > EPS2) {                   // candidates == {k1,k2}
                unsigned long long ka = exact_key(a, ffl, eel, emb, pos, k1);
                unsigned long long kb = exact_key(a, ffl, eel, emb, pos, k2);
                unsigned long long km = ka < kb ? ka : kb;
                kminl[pos] = (int)(km & 0xffffffffu);
            } else {
                wl[atomicAdd(wcnt, 1)] = pos;                        // rare: full exact scan
            }
        }
    }
    __syncthreads();

    // ---- phase 6: slow path — block-cooperative exact scan (256 threads x 2 codes)
    int nw = *wcnt;
    for (int i = 0; i < nw; ++i) {
        int pos = wl[i];
        unsigned long long ka = exact_key(a, ffl, eel, emb, pos, tid);
        unsigned long long kb = exact_key(a, ffl, eel, emb, pos, tid + 256);
        unsigned long long key = ka < kb ? ka : kb;
        #pragma unroll
        for (int m = 1; m < 64; m <<= 1) {
            unsigned long long p = __shfl_xor(key, m, 64);
            key = p < key ? p : key;
        }
        if (lane == 0) wred[w] = key;
        __syncthreads();
        if (tid == 0) {
            unsigned long long km = wred[0];
            #pragma unroll
            for (int j = 1; j < 4; ++j) km = wred[j] < km ? wred[j] : km;
            kminl[pos] = (int)(km & 0xffffffffu);
        }
        __syncthreads();
    }

    // ---- indices out (as float)
    if (tid < 128) out[IDX_OFF + n0 + tid] = (float)kminl[tid];

    // ---- quantized out (straight-through) + loss partial (proven epilogue)
    double lacc = 0.0;
    {
        const int col = (tid & 31) * 4;
        int iv[4];
        #pragma unroll
        for (int jj = 0; jj < 4; ++jj) iv[jj] = kminl[col + jj];
        float* ob = out + (long)b * CDIM * THW + r0;
        #pragma unroll
        for (int k = 0; k < 8; ++k) {
            int c = (tid >> 5) + 8 * k;
            float4 xv = *(const float4*)(a + c * MPOS + col);
            float4 ov;
            float q0 = emb[iv[0] * 64 + c];
            float d0 = __fsub_rn(q0, xv.x); ov.x = __fadd_rn(xv.x, d0); lacc += (double)__fmul_rn(d0, d0);
            float q1 = emb[iv[1] * 64 + c];
            float d1 = __fsub_rn(q1, xv.y); ov.y = __fadd_rn(xv.y, d1); lacc += (double)__fmul_rn(d1, d1);
            float q2 = emb[iv[2] * 64 + c];
            float d2 = __fsub_rn(q2, xv.z); ov.z = __fadd_rn(xv.z, d2); lacc += (double)__fmul_rn(d2, d2);
            float q3 = emb[iv[3] * 64 + c];
            float d3 = __fsub_rn(q3, xv.w); ov.w = __fadd_rn(xv.w, d3); lacc += (double)__fmul_rn(d3, d3);
            *(float4*)(ob + (long)c * THW + col) = ov;
        }
    }
    #pragma unroll
    for (int m = 1; m < 64; m <<= 1) lacc += __shfl_xor(lacc, m, 64);
    if (lane == 0) wsum[w] = lacc;
    __syncthreads();
    if (tid == 0) {
        double s = wsum[0] + wsum[1] + wsum[2] + wsum[3];
        atomicAdd(lossws, s);
    }
}

extern "C" __global__ void vq_finalize(const double* __restrict__ lossws,
                                       float* __restrict__ out) {
    if (threadIdx.x == 0) {
        float m = (float)(lossws[0] / (double)QOUT_N);
        out[LOSSOFF] = __fadd_rn(m, __fmul_rn(0.025f, m));
    }
}

extern "C" void kernel_launch(void* const* d_in, const int* in_sizes, int n_in,
                              void* d_out, int out_size, void* d_ws, size_t ws_size,
                              hipStream_t stream) {
    const float* x   = (const float*)d_in[0];
    const float* emb = (const float*)d_in[1];
    float* out = (float*)d_out;
    double* loss_ws = (double*)d_ws;
    float* ee_ws = (float*)((char*)d_ws + 256);
    unsigned short* ehi_ws  = (unsigned short*)((char*)d_ws + 4096);
    unsigned short* emid_ws = (unsigned short*)((char*)d_ws + 69632);

    hipMemsetAsync(d_ws, 0, sizeof(double), stream);
    hipLaunchKernelGGL(vq_prep, dim3(1), dim3(KCODES), 0, stream, emb, ee_ws, ehi_ws, emid_ws);

    dim3 grid(NPOS / MPOS);   // 4096
    dim3 block(NTHR);
    size_t shmem = 52808;
    hipLaunchKernelGGL(vq_main, grid, block, shmem, stream,
                       x, emb, out, loss_ws, ee_ws, ehi_ws, emid_ws);
    hipLaunchKernelGGL(vq_finalize, dim3(1), dim3(1), 0, stream,
                       (const double*)loss_ws, out);
}